// Round 3
// baseline (70.892 us; speedup 1.0000x reference)
//
#include <hip/hip_runtime.h>

// Dual-quaternion skinning. Round 3: 8 lanes per point (lane = skin index k).
// All heavy loads become per-lane coalesced exactly-once fetches (no LDS, no
// staging barrier). k-reduction via shfl_xor butterfly in 8-lane groups;
// epilogue computed redundantly by the group, outputs distributed across lanes.

__global__ void __launch_bounds__(256) dqskin_kernel(
    const float* __restrict__ sk_w,     // [N,8]
    const float* __restrict__ src_xyz,  // [N,3]
    const float* __restrict__ s_xyz,    // [N,8,3]
    const float* __restrict__ s_quat,   // [N,8,4] (w,x,y,z)
    const float* __restrict__ d_xyz,    // [N,8,3]
    const float* __restrict__ d_quat,   // [N,8,4]
    const float* __restrict__ dyn_o,    // [N]
    const float* __restrict__ src_R,    // [N,3,3]
    float* __restrict__ out,            // mu [N,3] then fr [N,3,3]
    int N)
{
    long long gid = (long long)blockIdx.x * blockDim.x + threadIdx.x;
    long long n = gid >> 3;
    int k = (int)(gid & 7);
    if (n >= N) return;

    long long nk = n * 8 + k;

    // ---- per-lane coalesced loads (this lane's bone only)
    float4 qi = reinterpret_cast<const float4*>(s_quat)[nk];
    float4 qj = reinterpret_cast<const float4*>(d_quat)[nk];
    float w_  = sk_w[nk];
    const float* sxp = s_xyz + nk * 3;
    const float* dxp = d_xyz + nk * 3;
    float px = sxp[0], py = sxp[1], pz = sxp[2];
    float e0 = dxp[0], e1 = dxp[1], e2 = dxp[2];

    // ---- quat -> rot (scale-invariant: two_s = 2/|q|^2)
    float Ri[9], Rj[9];
    {
        float s  = qi.x*qi.x + qi.y*qi.y + qi.z*qi.z + qi.w*qi.w;
        float ts = 2.0f / s;
        float qw=qi.x, qx=qi.y, qy=qi.z, qz=qi.w;
        Ri[0]=1.0f-ts*(qy*qy+qz*qz); Ri[1]=ts*(qx*qy-qz*qw); Ri[2]=ts*(qx*qz+qy*qw);
        Ri[3]=ts*(qx*qy+qz*qw); Ri[4]=1.0f-ts*(qx*qx+qz*qz); Ri[5]=ts*(qy*qz-qx*qw);
        Ri[6]=ts*(qx*qz-qy*qw); Ri[7]=ts*(qy*qz+qx*qw); Ri[8]=1.0f-ts*(qx*qx+qy*qy);
    }
    {
        float s  = qj.x*qj.x + qj.y*qj.y + qj.z*qj.z + qj.w*qj.w;
        float ts = 2.0f / s;
        float qw=qj.x, qx=qj.y, qy=qj.z, qz=qj.w;
        Rj[0]=1.0f-ts*(qy*qy+qz*qz); Rj[1]=ts*(qx*qy-qz*qw); Rj[2]=ts*(qx*qz+qy*qw);
        Rj[3]=ts*(qx*qy+qz*qw); Rj[4]=1.0f-ts*(qx*qx+qz*qz); Rj[5]=ts*(qy*qz-qx*qw);
        Rj[6]=ts*(qx*qz-qy*qw); Rj[7]=ts*(qy*qz+qx*qw); Rj[8]=1.0f-ts*(qx*qx+qy*qy);
    }

    // R = R_wj * R_wi^T
    float R[9];
    #pragma unroll
    for (int i = 0; i < 3; ++i)
        #pragma unroll
        for (int c = 0; c < 3; ++c)
            R[i*3+c] = Rj[i*3+0]*Ri[c*3+0] + Rj[i*3+1]*Ri[c*3+1] + Rj[i*3+2]*Ri[c*3+2];

    float t0 = e0 - (R[0]*px + R[1]*py + R[2]*pz);
    float t1 = e1 - (R[3]*px + R[4]*py + R[5]*pz);
    float t2 = e2 - (R[6]*px + R[7]*py + R[8]*pz);

    // matrix_to_quaternion
    float a0 = sqrtf(fmaxf(1.0f + R[0] + R[4] + R[8], 0.0f));
    float a1 = sqrtf(fmaxf(1.0f + R[0] - R[4] - R[8], 0.0f));
    float a2 = sqrtf(fmaxf(1.0f - R[0] + R[4] - R[8], 0.0f));
    float a3 = sqrtf(fmaxf(1.0f - R[0] - R[4] + R[8], 0.0f));
    int idx = 0; float best = a0;                  // first-max tie-break == jnp.argmax
    if (a1 > best) { best = a1; idx = 1; }
    if (a2 > best) { best = a2; idx = 2; }
    if (a3 > best) { best = a3; idx = 3; }

    float m01=R[1], m02=R[2], m10=R[3], m12=R[5], m20=R[6], m21=R[7];
    float cw = idx==0 ? a0*a0   : idx==1 ? m21-m12 : idx==2 ? m02-m20 : m10-m01;
    float cx = idx==0 ? m21-m12 : idx==1 ? a1*a1   : idx==2 ? m10+m01 : m20+m02;
    float cy = idx==0 ? m02-m20 : idx==1 ? m10+m01 : idx==2 ? a2*a2   : m21+m12;
    float cz = idx==0 ? m10-m01 : idx==1 ? m02+m20 : idx==2 ? m12+m21 : a3*a3;
    float inv = 1.0f / fmaxf(2.0f * best, 0.1f);
    float qrw = cw*inv, qrx = cx*inv, qry = cy*inv, qrz = cz*inv;

    // qd = 0.5 * qmul([0,t], qr)
    float qdw = 0.5f * (-t0*qrx - t1*qry - t2*qrz);
    float qdx = 0.5f * ( t0*qrw + t1*qrz - t2*qry);
    float qdy = 0.5f * (-t0*qrz + t1*qrw + t2*qrx);
    float qdz = 0.5f * ( t0*qry - t1*qrx + t2*qrw);

    float acc[8] = {w_*qrw, w_*qrx, w_*qry, w_*qrz, w_*qdw, w_*qdx, w_*qdy, w_*qdz};

    // ---- butterfly sum over the 8 lanes of this point (masks 1,2,4 stay in-group)
    #pragma unroll
    for (int m = 1; m <= 4; m <<= 1) {
        #pragma unroll
        for (int i = 0; i < 8; ++i)
            acc[i] += __shfl_xor(acc[i], m, 64);
    }

    // ---- epilogue (redundant across the 8 lanes of the group)
    float o = dyn_o[n];
    #pragma unroll
    for (int i = 0; i < 8; ++i) acc[i] *= o;
    acc[0] += 1.0f - o;

    float nr = sqrtf(acc[0]*acc[0] + acc[1]*acc[1] + acc[2]*acc[2] + acc[3]*acc[3]);
    nr = fmaxf(nr, 1e-4f);   // DQ_EPS
    float inr = 1.0f / nr;
    float uw = acc[0]*inr, ux = acc[1]*inr, uy = acc[2]*inr, uz = acc[3]*inr;
    float vw = acc[4]*inr, vx = acc[5]*inr, vy = acc[6]*inr, vz = acc[7]*inr;
    float dp = uw*vw + ux*vx + uy*vy + uz*vz;
    vw -= dp*uw; vx -= dp*ux; vy -= dp*uy; vz -= dp*uz;

    // dq2Rt (uw..uz is unit-norm; two_s = 2/|q|^2 still exact)
    float Rt[9];
    {
        float s  = uw*uw + ux*ux + uy*uy + uz*uz;
        float ts = 2.0f / s;
        Rt[0]=1.0f-ts*(uy*uy+uz*uz); Rt[1]=ts*(ux*uy-uz*uw); Rt[2]=ts*(ux*uz+uy*uw);
        Rt[3]=ts*(ux*uy+uz*uw); Rt[4]=1.0f-ts*(ux*ux+uz*uz); Rt[5]=ts*(uy*uz-ux*uw);
        Rt[6]=ts*(ux*uz-uy*uw); Rt[7]=ts*(uy*uz+ux*uw); Rt[8]=1.0f-ts*(ux*ux+uy*uy);
    }
    float tx = 2.0f * (-vw*ux + vx*uw - vy*uz + vz*uy);
    float ty = 2.0f * (-vw*uy + vx*uz + vy*uw - vz*ux);
    float tz = 2.0f * (-vw*uz - vx*uy + vy*ux + vz*uw);

    // mu = Rt @ src_xyz + t
    float gx = src_xyz[n*3+0], gy = src_xyz[n*3+1], gz = src_xyz[n*3+2];
    float mu0 = Rt[0]*gx + Rt[1]*gy + Rt[2]*gz + tx;
    float mu1 = Rt[3]*gx + Rt[4]*gy + Rt[5]*gz + ty;
    float mu2 = Rt[6]*gx + Rt[7]*gy + Rt[8]*gz + tz;

    // fr = Rt @ src_R
    const float* M = src_R + n * 9;
    float b0=M[0],b1=M[1],b2=M[2],b3=M[3],b4=M[4],b5=M[5],b6=M[6],b7=M[7],b8=M[8];
    float f0 = Rt[0]*b0 + Rt[1]*b3 + Rt[2]*b6;
    float f1 = Rt[0]*b1 + Rt[1]*b4 + Rt[2]*b7;
    float f2 = Rt[0]*b2 + Rt[1]*b5 + Rt[2]*b8;
    float f3 = Rt[3]*b0 + Rt[4]*b3 + Rt[5]*b6;
    float f4 = Rt[3]*b1 + Rt[4]*b4 + Rt[5]*b7;
    float f5 = Rt[3]*b2 + Rt[4]*b5 + Rt[5]*b8;
    float f6 = Rt[6]*b0 + Rt[7]*b3 + Rt[8]*b6;
    float f7 = Rt[6]*b1 + Rt[7]*b4 + Rt[8]*b7;
    float f8 = Rt[6]*b2 + Rt[7]*b5 + Rt[8]*b8;

    // ---- distribute the 12 outputs across the 8 lanes (branchless selects)
    long long frbase = (long long)N * 3 + n * 9;
    float v1 = k==0 ? mu0 : k==1 ? mu1 : k==2 ? mu2 :
               k==3 ? f0  : k==4 ? f1  : k==5 ? f2  : k==6 ? f3 : f4;
    long long a1a = (k < 3) ? (n*3 + k) : (frbase + (k - 3));
    out[a1a] = v1;
    if (k < 4) {
        float v2 = k==0 ? f5 : k==1 ? f6 : k==2 ? f7 : f8;
        out[frbase + 5 + k] = v2;
    }
}

extern "C" void kernel_launch(void* const* d_in, const int* in_sizes, int n_in,
                              void* d_out, int out_size, void* d_ws, size_t ws_size,
                              hipStream_t stream) {
    const float* sk_w    = (const float*)d_in[0];
    const float* src_xyz = (const float*)d_in[1];
    const float* s_xyz   = (const float*)d_in[2];
    const float* s_quat  = (const float*)d_in[3];
    const float* d_xyz   = (const float*)d_in[4];
    const float* d_quat  = (const float*)d_in[5];
    const float* dyn_o   = (const float*)d_in[6];
    const float* src_R   = (const float*)d_in[7];
    int N = in_sizes[6];   // dyn_o is [N]
    float* out = (float*)d_out;

    long long threads = (long long)N * 8;
    int blocks = (int)((threads + 255) / 256);
    hipLaunchKernelGGL(dqskin_kernel, dim3(blocks), dim3(256), 0, stream,
                       sk_w, src_xyz, s_xyz, s_quat, d_xyz, d_quat, dyn_o, src_R, out, N);
}